// Round 11
// baseline (357.631 us; speedup 1.0000x reference)
//
#include <hip/hip_runtime.h>
#include <hip/hip_cooperative_groups.h>

namespace cg = cooperative_groups;

// ---------------------------------------------------------------------------
// TextureAnalysisModule: x (16,3,1024,1024) f32
//  k_score : per-(patch,slice) |dx|,|dy| partial sums (round-6 verbatim;
//            measured ~33.6 us ~= per-CU VMEM-path floor)
//  k_fused : COOPERATIVE. phase1 finalize (1024 blocks) -> grid.sync ->
//            phase2 stable rank (32 blocks) -> grid.sync ->
//            phase3 output tiles (1344 blocks, R -> U direct -> 3-read SRM)
//  out: (2,16,3,224,224) f32
// ---------------------------------------------------------------------------

#define NSLICE 48
#define IMG    1048576
#define TILE   16

// --- K1: one block per (patch-row, slice); contiguous 32x1024 strip. -------
__global__ __launch_bounds__(256) void k_score(const float* __restrict__ x,
                                               double* __restrict__ part) {
  const int ph = blockIdx.x;   // patch row 0..31
  const int s  = blockIdx.y;   // slice 0..47
  const int t  = threadIdx.x;
  const float* base = x + (size_t)s * IMG + (size_t)ph * 32768 + 4 * t;

  double s1x = 0.0, s2x = 0.0, s1y = 0.0, s2y = 0.0;
  const bool has_d3 = (t & 7) != 7;   // col 4t+3 is not a patch boundary

#define LD(r) (*(const float4*)(base + (size_t)(r) * 1024))
#define DX(v) { float nx = __shfl_down((v).x, 1);                              \
    float d0 = fabsf((v).y-(v).x), d1 = fabsf((v).z-(v).y),                    \
          d2 = fabsf((v).w-(v).z);                                             \
    float d3 = has_d3 ? fabsf(nx-(v).w) : 0.f;                                 \
    s1x += (double)((d0+d1)+(d2+d3));                                          \
    s2x += (double)((d0*d0+d1*d1)+(d2*d2+d3*d3)); }
#define DY(a,b) { float e0 = fabsf((b).x-(a).x), e1 = fabsf((b).y-(a).y),      \
                        e2 = fabsf((b).z-(a).z), e3 = fabsf((b).w-(a).w);      \
    s1y += (double)((e0+e1)+(e2+e3));                                          \
    s2y += (double)((e0*e0+e1*e1)+(e2*e2+e3*e3)); }

  float4 v0 = LD(0);
  for (int r = 0; r < 32; r += 8) {
    float4 w1 = LD(r + 1), w2 = LD(r + 2), w3 = LD(r + 3), w4 = LD(r + 4);
    float4 w5 = LD(r + 5), w6 = LD(r + 6), w7 = LD(r + 7);
    float4 w8;
    const bool more = (r + 8 < 32);
    if (more) w8 = LD(r + 8);
    DX(v0); DX(w1); DX(w2); DX(w3); DX(w4); DX(w5); DX(w6); DX(w7);
    DY(v0, w1); DY(w1, w2); DY(w2, w3); DY(w3, w4);
    DY(w4, w5); DY(w5, w6); DY(w6, w7);
    if (more) { DY(w7, w8); v0 = w8; }
  }
#undef LD
#undef DX
#undef DY

#pragma unroll
  for (int off = 4; off > 0; off >>= 1) {
    s1x += __shfl_down(s1x, off, 8);
    s2x += __shfl_down(s2x, off, 8);
    s1y += __shfl_down(s1y, off, 8);
    s2y += __shfl_down(s2y, off, 8);
  }
  if ((t & 7) == 0) {
    const int p = ph * 32 + (t >> 3);
    part[(size_t)(0 * NSLICE + s) * 1024 + p] = s1x;
    part[(size_t)(1 * NSLICE + s) * 1024 + p] = s2x;
    part[(size_t)(2 * NSLICE + s) * 1024 + p] = s1y;
    part[(size_t)(3 * NSLICE + s) * 1024 + p] = s2y;
  }
}

// --- K2: cooperative fused finalize + rank + output. -----------------------
// grid = 1344 blocks x 256 threads, LDS ~21.9 KB -> 7 blocks/CU co-resident.
__global__ __launch_bounds__(256) void k_fused(const double* __restrict__ part,
                                               double* __restrict__ scores,
                                               int* __restrict__ sel,
                                               const float* __restrict__ x,
                                               float* __restrict__ out) {
  __shared__ __align__(16) char buf[21920];
  const int b = blockIdx.x;
  const int t = threadIdx.x;
  cg::grid_group grid = cg::this_grid();

  // ---- phase 1: finalize score for patch b (blocks 0..1023) ----
  if (b < 1024) {
    double* S = (double*)buf;            // [4]
    const int q    = t >> 6;             // wave = quantity
    const int lane = t & 63;
    double v = 0.0;
    if (lane < NSLICE)
      v = part[(size_t)(q * NSLICE + lane) * 1024 + b];
#pragma unroll
    for (int off = 32; off > 0; off >>= 1) v += __shfl_down(v, off);
    if (lane == 0) S[q] = v;
    __syncthreads();
    if (t == 0) {
      const double N = 47616.0;  // 16*3*32*31
      double mx = S[0] / N, my = S[2] / N;
      double vx = (S[1] - S[0] * S[0] / N) / (N - 1.0);
      double vy = (S[3] - S[2] * S[2] / N) / (N - 1.0);
      scores[b] = 0.25 * (mx + my) * (vx + vy);
    }
  }
  grid.sync();

  // ---- phase 2: stable rank (blocks 0..31; 8 lanes per candidate) ----
  if (b < 32) {
    double* sc = (double*)buf;           // [1024]
    for (int i = t; i < 1024; i += 256) sc[i] = scores[i];
    __syncthreads();
    const int c = b * 32 + (t >> 3);
    const double mine = sc[c];
    int rank = 0;
    for (int j = (t & 7); j < 1024; j += 8) {
      double vj = sc[j];
      rank += (vj < mine) || (vj == mine && j < c);
    }
#pragma unroll
    for (int off = 4; off > 0; off >>= 1) rank += __shfl_down(rank, off, 8);
    if ((t & 7) == 0) {
      if (rank < 9)          sel[9 + rank]    = c;
      else if (rank >= 1015) sel[rank - 1015] = c;
    }
  }
  grid.sync();

  // ---- phase 3: output tile b = blk*14 + ty ----
  {
    float* R   = (float*)(buf);                // [10][97]   3880 B
    float* U   = (float*)(buf + 3880);         // [18][225] 16200 B
    int*   i0t = (int*)  (buf + 20080);        // [224]       896 B
    float* frt = (float*)(buf + 20976);        // [224]       896 B
    int*  selm = (int*)  (buf + 21872);        // [9]          36 B

    const int ty  = b % 14;                    // 0..13
    const int blk = b / 14;                    // 0..95 = set*48 + (b*3+c)
    const int set = blk / 48;
    const int bc  = blk % 48;
    const int y0  = ty * TILE;

    if (t < 9) selm[t] = sel[set * 9 + t];
    if (t < 224) {
      // src coord = (t+0.5)*96/224 - 0.5 = (3t-2)/7 ; edge renorm == clamp
      int num = 3 * t - 2;
      int i0, fr7;
      if (num < 0) { i0 = 0; fr7 = 0; }
      else {
        i0 = num / 7; fr7 = num - i0 * 7;
        if (i0 >= 95) { i0 = 95; fr7 = 0; }
      }
      i0t[t] = i0;
      frt[t] = (float)fr7 * (1.0f / 7.0f);
    }
    __syncthreads();

    const int Ylo   = max(y0 - 1, 0);
    const int Yhi   = min(y0 + TILE, 223);
    const int sy_lo = i0t[Ylo];
    const int sy_hi = min(i0t[Yhi] + 1, 95);
    const int nrows = sy_hi - sy_lo + 1;       // <= 10

    // gather source rows
    const float* src = x + (size_t)bc * IMG;
    for (int idx = t; idx < nrows * 96; idx += 256) {
      int ry = idx / 96, xx = idx - ry * 96;
      int sy = sy_lo + ry;
      int gr = sy >> 5, i = sy & 31;
      int gc = xx >> 5, j = xx & 31;
      int pidx = selm[gr * 3 + gc];
      R[ry * 97 + xx] =
          src[(size_t)((pidx >> 5) * 32 + i) * 1024 + (pidx & 31) * 32 + j];
    }
    __syncthreads();

    // U (bilinear) directly from R; zero rows outside [0,224)
    for (int idx = t; idx < (TILE + 2) * 224; idx += 256) {
      int yy = idx / 224, X = idx - yy * 224;
      int Y = y0 - 1 + yy;
      float val = 0.f;
      if ((unsigned)Y < 224u) {
        int   a  = i0t[Y] - sy_lo;
        int   bb = min(i0t[Y] + 1, 95) - sy_lo;
        float fy = frt[Y];
        int   ix0 = i0t[X], ix1 = min(ix0 + 1, 95);
        float fx  = frt[X];
        float r00 = R[a * 97 + ix0],  r01 = R[a * 97 + ix1];
        float r10 = R[bb * 97 + ix0], r11 = R[bb * 97 + ix1];
        float top = r00 + fx * (r01 - r00);
        float bot = r10 + fx * (r11 - r10);
        val = top + fy * (bot - top);
      }
      U[yy * 225 + X] = val;
    }
    __syncthreads();

    // 3x3 SRM: acc = 3(A(x)+M(x-1)+M(x+1)) - A(x-1) - A(x+1) - 8 M(x)
    // A(x)=U[yy][x]+U[yy+2][x], M(x)=U[yy+1][x]. 14-px run per thread.
    const int yy = t >> 4;           // 0..15
    const int xs = (t & 15) * 14;    // 0,14,...,210
    const int y  = y0 + yy;
    float* o = out + (size_t)blk * (224 * 224) + (size_t)y * 224;

    const float* U0 = U + yy * 225;
    const float* U1 = U0 + 225;
    const float* U2 = U1 + 225;

    float aP, mP, aC, mC;
    if (xs > 0) {
      aP = U0[xs - 1] + U2[xs - 1];
      mP = U1[xs - 1];
    } else { aP = 0.f; mP = 0.f; }
    aC = U0[xs] + U2[xs];
    mC = U1[xs];

#pragma unroll
    for (int i = 0; i < 14; ++i) {
      const int xx = xs + i;
      float aN, mN;
      if (xx < 223) {
        aN = U0[xx + 1] + U2[xx + 1];
        mN = U1[xx + 1];
      } else { aN = 0.f; mN = 0.f; }
      o[xx] = 3.f * (aC + mP + mN) - (aP + aN) - 8.f * mC;
      aP = aC; aC = aN; mP = mC; mC = mN;
    }
  }
}

extern "C" void kernel_launch(void* const* d_in, const int* in_sizes, int n_in,
                              void* d_out, int out_size, void* d_ws, size_t ws_size,
                              hipStream_t stream) {
  const float* x = (const float*)d_in[0];
  float* out = (float*)d_out;

  double* part   = (double*)d_ws;                          // 4*48*1024*8 = 1.5 MB
  double* scores = (double*)((char*)d_ws + 1572864);       // 8 KB
  int*    sel    = (int*)((char*)d_ws + 1581056);          // 72 B

  k_score<<<dim3(32, 48), 256, 0, stream>>>(x, part);

  void* kargs[] = { (void*)&part, (void*)&scores, (void*)&sel,
                    (void*)&x, (void*)&out };
  hipLaunchCooperativeKernel((const void*)k_fused, dim3(1344), dim3(256),
                             kargs, 0, stream);
}

// Round 12
// 64.392 us; speedup vs baseline: 5.5540x; 5.5540x over previous
//
#include <hip/hip_runtime.h>

// ---------------------------------------------------------------------------
// TextureAnalysisModule: x (16,3,1024,1024) f32
//  k_score    : per-(patch,slice) |dx|,|dy| partial sums (round-6 verbatim)
//  k_finalize : one block per patch; 192 parallel loads + shfl tree (r6)
//  k_rank     : stable rank-by-counting, scatter top9/bot9 indices (r6)
//  k_output   : ONE WAVE PER OUTPUT ROW (21504 waves, 5376 blocks).
//               stage 3 recon rows -> 1 barrier -> per-px bilinear x3 rows
//               in regs -> 3x3 SRM via A/M + shfl -> coalesced store.
//  out: (2,16,3,224,224) f32
// ---------------------------------------------------------------------------

#define NSLICE 48
#define IMG    1048576

// --- K1: one block per (patch-row, slice); contiguous 32x1024 strip. -------
__global__ __launch_bounds__(256) void k_score(const float* __restrict__ x,
                                               double* __restrict__ part) {
  const int ph = blockIdx.x;   // patch row 0..31
  const int s  = blockIdx.y;   // slice 0..47
  const int t  = threadIdx.x;
  const float* base = x + (size_t)s * IMG + (size_t)ph * 32768 + 4 * t;

  double s1x = 0.0, s2x = 0.0, s1y = 0.0, s2y = 0.0;
  const bool has_d3 = (t & 7) != 7;   // col 4t+3 is not a patch boundary

#define LD(r) (*(const float4*)(base + (size_t)(r) * 1024))
#define DX(v) { float nx = __shfl_down((v).x, 1);                              \
    float d0 = fabsf((v).y-(v).x), d1 = fabsf((v).z-(v).y),                    \
          d2 = fabsf((v).w-(v).z);                                             \
    float d3 = has_d3 ? fabsf(nx-(v).w) : 0.f;                                 \
    s1x += (double)((d0+d1)+(d2+d3));                                          \
    s2x += (double)((d0*d0+d1*d1)+(d2*d2+d3*d3)); }
#define DY(a,b) { float e0 = fabsf((b).x-(a).x), e1 = fabsf((b).y-(a).y),      \
                        e2 = fabsf((b).z-(a).z), e3 = fabsf((b).w-(a).w);      \
    s1y += (double)((e0+e1)+(e2+e3));                                          \
    s2y += (double)((e0*e0+e1*e1)+(e2*e2+e3*e3)); }

  float4 v0 = LD(0);
  for (int r = 0; r < 32; r += 8) {
    float4 w1 = LD(r + 1), w2 = LD(r + 2), w3 = LD(r + 3), w4 = LD(r + 4);
    float4 w5 = LD(r + 5), w6 = LD(r + 6), w7 = LD(r + 7);
    float4 w8;
    const bool more = (r + 8 < 32);
    if (more) w8 = LD(r + 8);
    DX(v0); DX(w1); DX(w2); DX(w3); DX(w4); DX(w5); DX(w6); DX(w7);
    DY(v0, w1); DY(w1, w2); DY(w2, w3); DY(w3, w4);
    DY(w4, w5); DY(w5, w6); DY(w6, w7);
    if (more) { DY(w7, w8); v0 = w8; }
  }
#undef LD
#undef DX
#undef DY

#pragma unroll
  for (int off = 4; off > 0; off >>= 1) {
    s1x += __shfl_down(s1x, off, 8);
    s2x += __shfl_down(s2x, off, 8);
    s1y += __shfl_down(s1y, off, 8);
    s2y += __shfl_down(s2y, off, 8);
  }
  if ((t & 7) == 0) {
    const int p = ph * 32 + (t >> 3);
    part[(size_t)(0 * NSLICE + s) * 1024 + p] = s1x;
    part[(size_t)(1 * NSLICE + s) * 1024 + p] = s2x;
    part[(size_t)(2 * NSLICE + s) * 1024 + p] = s1y;
    part[(size_t)(3 * NSLICE + s) * 1024 + p] = s2y;
  }
}

// --- K2: one block per patch; wave q reduces quantity q over 48 slices. ----
__global__ __launch_bounds__(256) void k_finalize(const double* __restrict__ part,
                                                  double* __restrict__ scores) {
  const int p    = blockIdx.x;
  const int t    = threadIdx.x;
  const int q    = t >> 6;
  const int lane = t & 63;

  double v = 0.0;
  if (lane < NSLICE)
    v = part[(size_t)(q * NSLICE + lane) * 1024 + p];

#pragma unroll
  for (int off = 32; off > 0; off >>= 1) v += __shfl_down(v, off);

  __shared__ double S[4];
  if (lane == 0) S[q] = v;
  __syncthreads();

  if (t == 0) {
    const double N = 47616.0;  // 16*3*32*31
    double mx = S[0] / N, my = S[2] / N;
    double vx = (S[1] - S[0] * S[0] / N) / (N - 1.0);
    double vy = (S[3] - S[2] * S[2] / N) / (N - 1.0);
    scores[p] = 0.25 * (mx + my) * (vx + vy);
  }
}

// --- K3: stable rank; 8 lanes per candidate, 32 candidates per block. ------
__global__ __launch_bounds__(256) void k_rank(const double* __restrict__ scores,
                                              int* __restrict__ sel) {
  __shared__ double sc[1024];
  const int t = threadIdx.x;
  for (int i = t; i < 1024; i += 256) sc[i] = scores[i];
  __syncthreads();

  const int c = blockIdx.x * 32 + (t >> 3);
  const double mine = sc[c];
  int rank = 0;
  for (int j = (t & 7); j < 1024; j += 8) {
    double vj = sc[j];
    rank += (vj < mine) || (vj == mine && j < c);
  }
#pragma unroll
  for (int off = 4; off > 0; off >>= 1) rank += __shfl_down(rank, off, 8);
  if ((t & 7) == 0) {
    if (rank < 9)          sel[9 + rank]    = c;
    else if (rank >= 1015) sel[rank - 1015] = c;
  }
}

// --- K4: one wave per output row. 5376 blocks x 256 thr (4 waves). ---------
__global__ __launch_bounds__(256) void k_output(const float* __restrict__ x,
                                                const int* __restrict__ sel,
                                                float* __restrict__ out) {
  const int gb   = blockIdx.x;          // 0..5375
  const int blk  = gb / 56;             // image 0..95 = set*48 + bc
  const int y0   = (gb % 56) * 4;
  const int t    = threadIdx.x;
  const int w    = t >> 6;              // wave 0..3
  const int lane = t & 63;
  const int y    = y0 + w;              // output row 0..223

  const int set = blk / 48;
  const int bc  = blk % 48;

  __shared__ float S[4][3][96];         // per-wave staging of 3 recon rows

  // wave-uniform vertical geometry for U rows Y = y-1, y, y+1
  // i0(Y): num = 3Y-2; <0 -> (0,0); i0>=95 -> (95,0)
  int   ay[3], by[3];
  float fy[3];
  bool  vy[3];
  int s0;
  {
    const int Ylo  = max(y - 1, 0);
    int numl = 3 * Ylo - 2;
    s0 = numl < 0 ? 0 : min(numl / 7, 95);
#pragma unroll
    for (int q = 0; q < 3; ++q) {
      int Y  = y - 1 + q;
      vy[q]  = ((unsigned)Y < 224u);
      int Yc = min(max(Y, 0), 223);
      int num = 3 * Yc - 2;
      int i0  = num < 0 ? 0 : num / 7;
      float fr = num < 0 ? 0.f : (float)(num - 7 * i0) * (1.f / 7.f);
      if (i0 >= 95) { i0 = 95; fr = 0.f; }
      ay[q] = i0 - s0;                       // in {0,1}
      by[q] = min(i0 + 1, 95) - s0;          // in {0,1,2}
      fy[q] = fr;
    }
  }

  // stage recon rows s0, s0+1, s0+2 (clamped) : 72 float4
  const float* src = x + (size_t)bc * IMG;
  for (int ii = lane; ii < 72; ii += 64) {
    int r    = ii / 24;
    int c4   = (ii % 24) * 4;
    int srow = min(s0 + r, 95);
    int gr = srow >> 5, si = srow & 31;
    int gc = c4 >> 5,   j  = c4 & 31;
    int pidx = sel[set * 9 + gr * 3 + gc];   // tiny, L2-hot
    const float4 v = *(const float4*)&src[(size_t)((pidx >> 5) * 32 + si) * 1024
                                          + (pidx & 31) * 32 + j];
    *(float4*)&S[w][r][c4] = v;
  }
  __syncthreads();

  // per-pixel: horizontal lerp of the 3 staged rows, vertical lerp to 3 U
  // rows, fold into A = U(y-1)+U(y+1), M = U(y).
  float A[4], M[4];
#pragma unroll
  for (int k = 0; k < 4; ++k) {
    int xx = lane + (k << 6);
    int xc = min(xx, 223);
    int num = 3 * xc - 2;
    int ix0 = num < 0 ? 0 : num / 7;
    float fx = num < 0 ? 0.f : (float)(num - 7 * ix0) * (1.f / 7.f);
    if (ix0 >= 95) { ix0 = 95; fx = 0.f; }
    int ix1 = min(ix0 + 1, 95);

    float h0a = S[w][0][ix0], h0b = S[w][0][ix1];
    float h1a = S[w][1][ix0], h1b = S[w][1][ix1];
    float h2a = S[w][2][ix0], h2b = S[w][2][ix1];
    float h0 = h0a + fx * (h0b - h0a);
    float h1 = h1a + fx * (h1b - h1a);
    float h2 = h2a + fx * (h2b - h2a);

    float U3[3];
#pragma unroll
    for (int q = 0; q < 3; ++q) {
      float ha = (ay[q] == 0) ? h0 : h1;
      float hb = (by[q] == 0) ? h0 : ((by[q] == 1) ? h1 : h2);
      U3[q] = vy[q] ? (ha + fy[q] * (hb - ha)) : 0.f;
    }
    A[k] = U3[0] + U3[2];
    M[k] = U3[1];
  }

  // 3x3 SRM: out = 3(A(x)+M(x-1)+M(x+1)) - A(x-1) - A(x+1) - 8 M(x)
  float* o = out + (size_t)blk * (224 * 224) + (size_t)y * 224;
#pragma unroll
  for (int k = 0; k < 4; ++k) {
    int xx = lane + (k << 6);

    float aL = __shfl_up(A[k], 1);
    float mL = __shfl_up(M[k], 1);
    float aP = (k > 0) ? __shfl(A[k - 1], 63) : 0.f;
    float mP = (k > 0) ? __shfl(M[k - 1], 63) : 0.f;
    if (lane == 0) { aL = aP; mL = mP; }

    float aR = __shfl_down(A[k], 1);
    float mR = __shfl_down(M[k], 1);
    float aN = (k < 3) ? __shfl(A[k + 1], 0) : 0.f;
    float mN = (k < 3) ? __shfl(M[k + 1], 0) : 0.f;
    if (lane == 63) { aR = aN; mR = mN; }

    if (xx == 0)   { aL = 0.f; mL = 0.f; }
    if (xx == 223) { aR = 0.f; mR = 0.f; }

    if (xx < 224)
      o[xx] = 3.f * (A[k] + mL + mR) - (aL + aR) - 8.f * M[k];
  }
}

extern "C" void kernel_launch(void* const* d_in, const int* in_sizes, int n_in,
                              void* d_out, int out_size, void* d_ws, size_t ws_size,
                              hipStream_t stream) {
  const float* x = (const float*)d_in[0];
  float* out = (float*)d_out;

  double* part   = (double*)d_ws;                          // 4*48*1024*8 = 1.5 MB
  double* scores = (double*)((char*)d_ws + 1572864);       // 8 KB
  int*    sel    = (int*)((char*)d_ws + 1581056);          // 72 B

  k_score   <<<dim3(32, 48), 256, 0, stream>>>(x, part);
  k_finalize<<<1024, 256, 0, stream>>>(part, scores);
  k_rank    <<<32, 256, 0, stream>>>(scores, sel);
  k_output  <<<5376, 256, 0, stream>>>(x, sel, out);
}